// Round 9
// baseline (186.236 us; speedup 1.0000x reference)
//
#include <hip/hip_runtime.h>
#include <math.h>

// Problem constants (fixed by the reference)
#define BB   64
#define NN   131072
#define KTAPS 5
#define TILE 1024              // elements per chunk (256 threads x 4)
#define CHUNKS 4
#define SPAN (TILE * CHUNKS)   // 4096 elements per block
#define NTHREADS 256

// 2*pi / sampling_freq
#define ANG_PER_HZ 2.0453077171808549e-7f   // float(2*pi/30720000.0)
// 10*log10(1.5)
#define EBNO_OFF   1.7609125905568124f
// log2(10)/20
#define L2TEN_OVER20 0.16609640474436813f

typedef float f32x4 __attribute__((ext_vector_type(4)));

// x-only prefetch state: 16 VGPRs per buffer
struct XBuf { float4 xr0, xi0; float2 xrL, xrR, xiL, xiR; };

__device__ __forceinline__ XBuf load_x(const float* __restrict__ xr,
                                       const float* __restrict__ xi, int base) {
    const int aL = (base == 0)      ? 0      : base - 2;   // clamp addr; value masked
    const int aR = (base == NN - 4) ? NN - 2 : base + 4;
    XBuf v;
    v.xrL = *reinterpret_cast<const float2*>(xr + aL);
    v.xr0 = *reinterpret_cast<const float4*>(xr + base);
    v.xrR = *reinterpret_cast<const float2*>(xr + aR);
    v.xiL = *reinterpret_cast<const float2*>(xi + aL);
    v.xi0 = *reinterpret_cast<const float4*>(xi + base);
    v.xiR = *reinterpret_cast<const float2*>(xi + aR);
    return v;
}

__global__ __launch_bounds__(NTHREADS) void wc_kernel(
    const float* __restrict__ x_real,  const float* __restrict__ x_imag,
    const float* __restrict__ ebno_db, const float* __restrict__ cfo_u,
    const float* __restrict__ taps_real, const float* __restrict__ taps_imag,
    const float* __restrict__ noise_real, const float* __restrict__ noise_imag,
    float* __restrict__ out)
{
    const int b    = blockIdx.y;
    const int col0 = blockIdx.x * SPAN + threadIdx.x * 4;
    const size_t rowoff = (size_t)b * NN;

    const float* __restrict__ xr = x_real + rowoff;
    const float* __restrict__ xi = x_imag + rowoff;
    const float* __restrict__ nr = noise_real + rowoff;
    const float* __restrict__ ni = noise_imag + rowoff;
    float* __restrict__ outr = out + rowoff;
    float* __restrict__ outi = out + (size_t)BB * NN + rowoff;

    // ---- issue chunk-0 x loads first; scalars resolve under their latency ----
    XBuf A = load_x(xr, xi, col0);

    // ---- per-batch scalars (block-uniform -> s_load / SGPR) ----
    const float cfo     = cfo_u[b];
    const float delta_f = (cfo * 2.0f - 1.0f) * 0.05f * 15000.0f;
    const float ang     = delta_f * ANG_PER_HZ;        // radians per sample
    const float snr     = ebno_db[b] + EBNO_OFF;
    const float scale   = 0.5f * exp2f(-snr * L2TEN_OVER20);

    float tr[KTAPS], ti[KTAPS];
#pragma unroll
    for (int k = 0; k < KTAPS; ++k) {
        tr[k] = taps_real[b * KTAPS + k];
        ti[k] = taps_imag[b * KTAPS + k];
    }

    float sA, cA;
    __sincosf(ang, &sA, &cA);

    XBuf B = A;
#pragma unroll
    for (int ch = 0; ch < CHUNKS; ++ch) {
        const int base = col0 + ch * TILE;

        // prefetch next chunk's x (in flight during this chunk's compute)
        if (ch + 1 < CHUNKS) B = load_x(xr, xi, base + TILE);

        // noise for this chunk: nontemporal loads (read-once), hidden by conv
        f32x4 nr4 = __builtin_nontemporal_load(reinterpret_cast<const f32x4*>(nr + base));
        f32x4 ni4 = __builtin_nontemporal_load(reinterpret_cast<const f32x4*>(ni + base));

        // per-chunk trig anchor (phase <= ~20 rad, __sincosf is plenty)
        float s, c;
        __sincosf(ang * (float)(base - 2), &s, &c);

        const bool lok = (base != 0);
        const bool rok = (base != NN - 4);

        // window x[base-2 .. base+5]
        float ur[8], ui[8];
        ur[0] = lok ? A.xrL.x : 0.0f;  ui[0] = lok ? A.xiL.x : 0.0f;
        ur[1] = lok ? A.xrL.y : 0.0f;  ui[1] = lok ? A.xiL.y : 0.0f;
        ur[2] = A.xr0.x;  ui[2] = A.xi0.x;
        ur[3] = A.xr0.y;  ui[3] = A.xi0.y;
        ur[4] = A.xr0.z;  ui[4] = A.xi0.z;
        ur[5] = A.xr0.w;  ui[5] = A.xi0.w;
        ur[6] = rok ? A.xrR.x : 0.0f;  ui[6] = rok ? A.xiR.x : 0.0f;
        ur[7] = rok ? A.xrR.y : 0.0f;  ui[7] = rok ? A.xiR.y : 0.0f;

        // CFO rotation via angle-addition recurrence (phase = ang*(base-2+j))
        float wr[8], wi[8];
#pragma unroll
        for (int j = 0; j < 8; ++j) {
            wr[j] = ur[j] * c - ui[j] * s;
            wi[j] = ur[j] * s + ui[j] * c;
            float cn = c * cA - s * sA;
            float sn = s * cA + c * sA;
            c = cn; s = sn;
        }

        // 5-tap complex conv (cross-correlation) + AWGN
        f32x4 yr4, yi4;
#pragma unroll
        for (int j = 0; j < 4; ++j) {
            float ar = 0.0f, ai = 0.0f;
#pragma unroll
            for (int k = 0; k < KTAPS; ++k) {
                ar = fmaf(tr[k], wr[j + k], ar);
                ar = fmaf(-ti[k], wi[j + k], ar);
                ai = fmaf(ti[k], wr[j + k], ai);
                ai = fmaf(tr[k], wi[j + k], ai);
            }
            yr4[j] = fmaf(nr4[j], scale, ar);
            yi4[j] = fmaf(ni4[j], scale, ai);
        }

        // plain stores: ack at L2 (NT stores appeared to park waves at endpgm)
        *reinterpret_cast<f32x4*>(outr + base) = yr4;
        *reinterpret_cast<f32x4*>(outi + base) = yi4;

        A = B;
    }
}

extern "C" void kernel_launch(void* const* d_in, const int* in_sizes, int n_in,
                              void* d_out, int out_size, void* d_ws, size_t ws_size,
                              hipStream_t stream) {
    const float* x_real     = (const float*)d_in[0];
    const float* x_imag     = (const float*)d_in[1];
    const float* ebno_db    = (const float*)d_in[2];
    const float* cfo_u      = (const float*)d_in[3];
    const float* taps_real  = (const float*)d_in[4];
    const float* taps_imag  = (const float*)d_in[5];
    const float* noise_real = (const float*)d_in[6];
    const float* noise_imag = (const float*)d_in[7];

    dim3 grid(NN / SPAN, BB);   // 32 x 64 = 2048 blocks = 8/CU, one generation
    wc_kernel<<<grid, NTHREADS, 0, stream>>>(
        x_real, x_imag, ebno_db, cfo_u, taps_real, taps_imag,
        noise_real, noise_imag, (float*)d_out);
}

// Round 11
// 177.444 us; speedup vs baseline: 1.0495x; 1.0495x over previous
//
#include <hip/hip_runtime.h>
#include <math.h>

// Problem constants (fixed by the reference)
#define BB   64
#define NN   131072
#define KTAPS 5
#define TILE 1024          // elements per block (256 threads x 4)
#define NTHREADS 256
#define NXCD 8

// 2*pi / sampling_freq
#define ANG_PER_HZ 2.0453077171808549e-7f   // float(2*pi/30720000.0)
// 10*log10(1.5)
#define EBNO_OFF   1.7609125905568124f
// log2(10)/20
#define L2TEN_OVER20 0.16609640474436813f

typedef float f32x4 __attribute__((ext_vector_type(4)));
typedef float f32x2 __attribute__((ext_vector_type(2)));

__global__ __launch_bounds__(NTHREADS) void wc_kernel(
    const float* __restrict__ x_real,  const float* __restrict__ x_imag,
    const float* __restrict__ ebno_db, const float* __restrict__ cfo_u,
    const float* __restrict__ taps_real, const float* __restrict__ taps_imag,
    const float* __restrict__ noise_real, const float* __restrict__ noise_imag,
    float* __restrict__ out)
{
    const int b  = blockIdx.y;
    // XCD-bijective swizzle: gridDim.x = 128 = 8 XCDs x 16 chunks.
    // HW round-robins linear block id over XCDs (id%8); remap so each XCD
    // covers a CONTIGUOUS 1/8 of the row for all 6 streams.
    const int bx = (blockIdx.x & (NXCD - 1)) * (128 / NXCD) + (blockIdx.x >> 3);
    const int base = bx * TILE + threadIdx.x * 4;          // my 4 elements
    const size_t rowoff = (size_t)b * NN;

    const float* __restrict__ xr = x_real + rowoff;
    const float* __restrict__ xi = x_imag + rowoff;

    // Clamped halo addresses (values masked to 0 at row edges).
    const int aL = (base == 0)      ? 0      : base - 2;
    const int aR = (base == NN - 4) ? NN - 2 : base + 4;

    // ---- all 8 global loads issued back-to-back ----
    // body + noise: nontemporal (read-once; don't churn L2).
    // halos: cached (the only reused bytes).
    const f32x4 xr0 = __builtin_nontemporal_load(reinterpret_cast<const f32x4*>(xr + base));
    const f32x4 xi0 = __builtin_nontemporal_load(reinterpret_cast<const f32x4*>(xi + base));
    const f32x4 nr4 = __builtin_nontemporal_load(reinterpret_cast<const f32x4*>(noise_real + rowoff + base));
    const f32x4 ni4 = __builtin_nontemporal_load(reinterpret_cast<const f32x4*>(noise_imag + rowoff + base));
    const float2 xrL = *reinterpret_cast<const float2*>(xr + aL);
    const float2 xrR = *reinterpret_cast<const float2*>(xr + aR);
    const float2 xiL = *reinterpret_cast<const float2*>(xi + aL);
    const float2 xiR = *reinterpret_cast<const float2*>(xi + aR);

    // ---- per-batch scalars + trig: execute UNDER the load latency ----
    const float cfo     = cfo_u[b];
    const float delta_f = (cfo * 2.0f - 1.0f) * 0.05f * 15000.0f;
    const float ang     = delta_f * ANG_PER_HZ;        // radians per sample
    const float snr     = ebno_db[b] + EBNO_OFF;
    const float scale   = 0.5f * exp2f(-snr * L2TEN_OVER20);

    float tr[KTAPS], ti[KTAPS];
#pragma unroll
    for (int k = 0; k < KTAPS; ++k) {
        tr[k] = taps_real[b * KTAPS + k];
        ti[k] = taps_imag[b * KTAPS + k];
    }

    float sA, cA, s, c;
    __sincosf(ang, &sA, &cA);
    __sincosf(ang * (float)(base - 2), &s, &c);

    // ---- window x[base-2 .. base+5], branchless edge masks ----
    const bool lok = (base != 0);
    const bool rok = (base != NN - 4);

    float ur[8], ui[8];
    ur[0] = lok ? xrL.x : 0.0f;  ui[0] = lok ? xiL.x : 0.0f;
    ur[1] = lok ? xrL.y : 0.0f;  ui[1] = lok ? xiL.y : 0.0f;
    ur[2] = xr0.x;  ui[2] = xi0.x;
    ur[3] = xr0.y;  ui[3] = xi0.y;
    ur[4] = xr0.z;  ui[4] = xi0.z;
    ur[5] = xr0.w;  ui[5] = xi0.w;
    ur[6] = rok ? xrR.x : 0.0f;  ui[6] = rok ? xiR.x : 0.0f;
    ur[7] = rok ? xrR.y : 0.0f;  ui[7] = rok ? xiR.y : 0.0f;

    // ---- CFO rotation via angle-addition recurrence (phase = ang*(base-2+j))
    float wr[8], wi[8];
#pragma unroll
    for (int j = 0; j < 8; ++j) {
        wr[j] = ur[j] * c - ui[j] * s;
        wi[j] = ur[j] * s + ui[j] * c;
        float cn = c * cA - s * sA;
        float sn = s * cA + c * sA;
        c = cn; s = sn;
    }

    // ---- 5-tap complex conv (cross-correlation) + AWGN ----
    const float nr_[4] = {nr4.x, nr4.y, nr4.z, nr4.w};
    const float ni_[4] = {ni4.x, ni4.y, ni4.z, ni4.w};

    f32x4 yr4, yi4;
#pragma unroll
    for (int j = 0; j < 4; ++j) {
        float ar = 0.0f, ai = 0.0f;
#pragma unroll
        for (int k = 0; k < KTAPS; ++k) {
            ar = fmaf(tr[k], wr[j + k], ar);
            ar = fmaf(-ti[k], wi[j + k], ar);
            ai = fmaf(ti[k], wr[j + k], ai);
            ai = fmaf(tr[k], wi[j + k], ai);
        }
        yr4[j] = fmaf(nr_[j], scale, ar);
        yi4[j] = fmaf(ni_[j], scale, ai);
    }

    // ---- nontemporal stores: write-once output, keep L2 for reads ----
    __builtin_nontemporal_store(yr4, reinterpret_cast<f32x4*>(out + rowoff + base));
    __builtin_nontemporal_store(yi4, reinterpret_cast<f32x4*>(out + (size_t)BB * NN + rowoff + base));
}

extern "C" void kernel_launch(void* const* d_in, const int* in_sizes, int n_in,
                              void* d_out, int out_size, void* d_ws, size_t ws_size,
                              hipStream_t stream) {
    const float* x_real     = (const float*)d_in[0];
    const float* x_imag     = (const float*)d_in[1];
    const float* ebno_db    = (const float*)d_in[2];
    const float* cfo_u      = (const float*)d_in[3];
    const float* taps_real  = (const float*)d_in[4];
    const float* taps_imag  = (const float*)d_in[5];
    const float* noise_real = (const float*)d_in[6];
    const float* noise_imag = (const float*)d_in[7];

    dim3 grid(NN / TILE, BB);   // 128 x 64 = 8192 blocks
    wc_kernel<<<grid, NTHREADS, 0, stream>>>(
        x_real, x_imag, ebno_db, cfo_u, taps_real, taps_imag,
        noise_real, noise_imag, (float*)d_out);
}